// Round 16
// baseline (485.109 us; speedup 1.0000x reference)
//
#include <hip/hip_runtime.h>
#include <cmath>

#define N_NODES 50000
#define N_EDGES 100000
#define HALF_N  25000
#define DIM     256
#define NDEPTH  2
#define MAXDEG  64

// per-layer weight-buffer offsets (bf16 elements), chunk-packed layouts
#define WT_QKVE 0          // 6 tiles x [64 k8][128 n] bf16x8 (q | k/v interleaved)
#define WT_WO   393216     // 2 tiles x [64 k8][128 n]  K=512: [Wo ; Weff]
#define WT_W1   524288     // 8 chunks x [32 k8][128 n]
#define WT_W2   786432     // 8 chunks x [16 k8][256 n]
#define WT_LAYER 1048576

typedef __bf16 bf16;
typedef bf16 bf16x8 __attribute__((ext_vector_type(8)));
typedef bf16 bf16x4 __attribute__((ext_vector_type(4)));
typedef float f32x4 __attribute__((ext_vector_type(4)));

// LDS-only barrier: does NOT drain vmcnt (global loads stay in flight).
__device__ __forceinline__ void lds_barrier() {
  asm volatile("s_waitcnt lgkmcnt(0)" ::: "memory");
  __builtin_amdgcn_s_barrier();
  __builtin_amdgcn_sched_barrier(0);
}

__device__ __forceinline__ float wave_sum(float v) {
  v += __shfl_xor(v, 1);
  v += __shfl_xor(v, 2);
  v += __shfl_xor(v, 4);
  v += __shfl_xor(v, 8);
  v += __shfl_xor(v, 16);
  v += __shfl_xor(v, 32);
  return v;
}

// 7-op GELU: x * sigmoid(1.59577*(x + 0.044715 x^3)) via single exp2.
__device__ __forceinline__ float fast_gelu(float x) {
  float p = x * x;
  float q = fmaf(p, -0.10294437f, -2.3022112f);
  float e = exp2f(x * q);
  return x * __builtin_amdgcn_rcpf(1.0f + e);
}

// ---------------- layer-0 LN1: x -> A2 left half (stride 512) ----------------
__global__ void ln0_kernel(const float* __restrict__ in, const float* __restrict__ g,
                           const float* __restrict__ b, bf16* __restrict__ A2) {
  int row = blockIdx.x * 4 + (threadIdx.x >> 6);
  if (row >= HALF_N) return;
  int lane = threadIdx.x & 63;
  float4 x = reinterpret_cast<const float4*>(in + (size_t)row * DIM)[lane];
  float mu = wave_sum(x.x + x.y + x.z + x.w) * (1.0f / DIM);
  float d0 = x.x - mu, d1 = x.y - mu, d2 = x.z - mu, d3 = x.w - mu;
  float var = wave_sum(d0*d0 + d1*d1 + d2*d2 + d3*d3) * (1.0f / DIM);
  float r = rsqrtf(var + 1e-5f);
  float4 gv = reinterpret_cast<const float4*>(g)[lane];
  float4 bv = reinterpret_cast<const float4*>(b)[lane];
  bf16x4 o;
  o[0] = (bf16)(d0 * r * gv.x + bv.x);
  o[1] = (bf16)(d1 * r * gv.y + bv.y);
  o[2] = (bf16)(d2 * r * gv.z + bv.z);
  o[3] = (bf16)(d3 * r * gv.w + bv.w);
  *reinterpret_cast<bf16x4*>(A2 + (size_t)row * 512 + lane * 4) = o;
}

// ---------------- N-loop MFMA GEMM (qkv): 512 threads, 8 waves, ni=1 ---------
template<int KK, int NJ>
__global__ __launch_bounds__(512, 2) void gemm_nloop(
    const bf16* __restrict__ A, const bf16* __restrict__ Wp,
    const float* __restrict__ bias, bf16* __restrict__ C, int M) {
  constexpr int STEPS = KK / 64;
  __shared__ bf16x8 As[KK * 8];        // KK=512 -> 64 KB
  __shared__ bf16 Cs[64 * 128];        // 16 KB
  const int tid = threadIdx.x;
  const int lane = tid & 63, wv = tid >> 6;
  const int lm = lane & 15, kb = (lane >> 4) & 3;
  const int row0 = blockIdx.x * 64;
#pragma unroll
  for (int i = 0; i < KK / 64; ++i) {
    int idx = tid + i * 512;
    int row = idx & 63, k8 = idx >> 6;
    int rga = row0 + row; if (rga >= M) rga = M - 1;
    As[idx] = *reinterpret_cast<const bf16x8*>(A + (size_t)rga * KK + k8 * 8);
  }
  const bf16x8* wb = reinterpret_cast<const bf16x8*>(Wp) + kb * 128 + wv * 16 + lm;
  bf16x8 pfr = wb[0];
  lds_barrier();
  for (int jn = 0; jn < NJ; ++jn) {
    f32x4 acc[4] = {};
    __builtin_amdgcn_s_setprio(1);
#pragma unroll
    for (int st = 0; st < STEPS; ++st) {
#pragma unroll
      for (int ks = 0; ks < 2; ++ks) {
        bf16x8 bfr = (st == 0 && ks == 0)
                   ? pfr
                   : wb[(size_t)jn * (KK * 16) + st * 1024 + ks * 512];
        bf16x8 af[4];
#pragma unroll
        for (int mi = 0; mi < 4; ++mi)
          af[mi] = As[(st * 8 + ks * 4 + kb) * 64 + mi * 16 + lm];
#pragma unroll
        for (int mi = 0; mi < 4; ++mi)
          acc[mi] = __builtin_amdgcn_mfma_f32_16x16x32_bf16(af[mi], bfr, acc[mi], 0, 0, 0);
      }
    }
    __builtin_amdgcn_s_setprio(0);
    if (jn + 1 < NJ) pfr = wb[(size_t)(jn + 1) * (KK * 16)];
    lds_barrier();
    {
      int c = wv * 16 + lm;
      float bval = bias[jn * 128 + c];
#pragma unroll
      for (int mi = 0; mi < 4; ++mi)
#pragma unroll
        for (int e = 0; e < 4; ++e) {
          int r = mi * 16 + kb * 4 + e;
          Cs[r * 128 + c] = (bf16)(acc[mi][e] + bval);
        }
    }
    lds_barrier();
    bf16x8* C8 = reinterpret_cast<bf16x8*>(C);
    const bf16x8* Cs8 = (const bf16x8*)Cs;
#pragma unroll
    for (int i = 0; i < 2; ++i) {
      int idx = tid + i * 512;
      int row = idx >> 4, c8 = idx & 15;
      int grow = row0 + row;
      if (grow < M) C8[(size_t)grow * (NJ * 16) + jn * 16 + c8] = Cs8[row * 16 + c8];
    }
  }
}

// ---------------- Wo GEMM (K=512: [agg|x] @ [Wo;Weff]) + gr1 + LN2 ----------
__global__ __launch_bounds__(256, 2) void wo_fused(
    const bf16* __restrict__ agg, const bf16* __restrict__ A2,
    const bf16* __restrict__ Wp, const float* __restrict__ bvec,
    const float* __restrict__ bo, const int* __restrict__ deg,
    const float* __restrict__ gattn, const float* __restrict__ ln2g,
    const float* __restrict__ ln2b, float* __restrict__ nodes,
    bf16* __restrict__ xn, int rows) {
  __shared__ bf16x8 As[2048];          // agg tile [32 k8][64 row] 32 KB
  __shared__ bf16 Cs[64 * 256];        // 32 KB, XOR-swizzled chunks
  const int tid = threadIdx.x;
  const int lane = tid & 63, wv = tid >> 6;
  const int row0 = blockIdx.x * 64;
  float4 w0 = reinterpret_cast<const float4*>(gattn)[lane];
  float4 w1 = reinterpret_cast<const float4*>(gattn + 256)[lane];
  float4 w2 = reinterpret_cast<const float4*>(gattn + 512)[lane];
  float4 wa, wbv;
  wa.x = w0.x + w2.x; wa.y = w0.y + w2.y; wa.z = w0.z + w2.z; wa.w = w0.w + w2.w;
  wbv.x = w1.x - w2.x; wbv.y = w1.y - w2.y; wbv.z = w1.z - w2.z; wbv.w = w1.w - w2.w;
  float4 gv = reinterpret_cast<const float4*>(ln2g)[lane];
  float4 bv = reinterpret_cast<const float4*>(ln2b)[lane];
  if (row0 < HALF_N) {
    const int wr = wv >> 1, wc = wv & 1;
    const int lm = lane & 15, kb = (lane >> 4) & 3;
#pragma unroll
    for (int i = 0; i < 8; ++i) {
      int idx = tid + i * 256;
      int row = idx & 63, k8 = idx >> 6;
      int rga = row0 + row; if (rga >= HALF_N) rga = HALF_N - 1;
      As[idx] = *reinterpret_cast<const bf16x8*>(agg + (size_t)rga * 256 + k8 * 8);
    }
    bf16x8 afx[2][8];
#pragma unroll
    for (int mi = 0; mi < 2; ++mi) {
      int row = row0 + wr * 32 + mi * 16 + lm;
      if (row >= HALF_N) row = HALF_N - 1;
      const bf16* pa = A2 + (size_t)row * 512 + 256 + kb * 8;
#pragma unroll
      for (int t = 0; t < 8; ++t)
        afx[mi][t] = *reinterpret_cast<const bf16x8*>(pa + t * 32);
    }
    lds_barrier();
    const bf16x8* wb = reinterpret_cast<const bf16x8*>(Wp) + kb * 128 + wc * 64 + lm;
    for (int jn = 0; jn < 2; ++jn) {
      f32x4 acc[2][4] = {};
      __builtin_amdgcn_s_setprio(1);
#pragma unroll
      for (int st = 0; st < 8; ++st) {
#pragma unroll
        for (int ks = 0; ks < 2; ++ks) {
          bf16x8 bfr[4], af[2];
#pragma unroll
          for (int ni = 0; ni < 4; ++ni)
            bfr[ni] = wb[jn * 8192 + (st * 8 + ks * 4) * 128 + ni * 16];
#pragma unroll
          for (int mi = 0; mi < 2; ++mi)
            af[mi] = (st < 4) ? As[(st * 8 + ks * 4 + kb) * 64 + wr * 32 + mi * 16 + lm]
                              : afx[mi][(st - 4) * 2 + ks];
#pragma unroll
          for (int mi = 0; mi < 2; ++mi)
#pragma unroll
            for (int ni = 0; ni < 4; ++ni)
              acc[mi][ni] = __builtin_amdgcn_mfma_f32_16x16x32_bf16(af[mi], bfr[ni], acc[mi][ni], 0, 0, 0);
        }
      }
      __builtin_amdgcn_s_setprio(0);
#pragma unroll
      for (int ni = 0; ni < 4; ++ni) {
        int cfull = jn * 128 + wc * 64 + ni * 16 + lm;
        float bval = bvec[cfull];
#pragma unroll
        for (int mi = 0; mi < 2; ++mi)
#pragma unroll
          for (int e = 0; e < 4; ++e) {
            int r = wr * 32 + mi * 16 + kb * 4 + e;
            int ch = (cfull >> 3) ^ (r & 7);
            Cs[r * 256 + ch * 8 + (cfull & 7)] = (bf16)(acc[mi][ni][e] + bval);
          }
      }
    }
    lds_barrier();
    for (int pass = 0; pass < 16; ++pass) {
      int r = pass * 4 + wv;
      int grow = row0 + r;
      float x0, x1, x2, x3;
      if (grow >= HALF_N || deg[grow] == 0) {
        float4 bo4 = reinterpret_cast<const float4*>(bo)[lane];
        x0 = bo4.x; x1 = bo4.y; x2 = bo4.z; x3 = bo4.w;
      } else {
        int ch = (lane >> 1) ^ (r & 7);
        bf16x4 c4 = *reinterpret_cast<const bf16x4*>(Cs + r * 256 + ch * 8 + (lane & 1) * 4);
        x0 = (float)c4[0]; x1 = (float)c4[1]; x2 = (float)c4[2]; x3 = (float)c4[3];
      }
      float4 rv = reinterpret_cast<const float4*>(nodes + (size_t)grow * 256)[lane];
      float dot = x0 * wa.x + rv.x * wbv.x + x1 * wa.y + rv.y * wbv.y
                + x2 * wa.z + rv.z * wbv.z + x3 * wa.w + rv.w * wbv.w;
      dot = wave_sum(dot);
      float gate = 1.0f / (1.0f + __expf(-dot));
      float n0 = fmaf(x0 - rv.x, gate, rv.x);
      float n1 = fmaf(x1 - rv.y, gate, rv.y);
      float n2 = fmaf(x2 - rv.z, gate, rv.z);
      float n3 = fmaf(x3 - rv.w, gate, rv.w);
      float4 o; o.x = n0; o.y = n1; o.z = n2; o.w = n3;
      reinterpret_cast<float4*>(nodes + (size_t)grow * 256)[lane] = o;
      float mu = wave_sum(n0 + n1 + n2 + n3) * (1.0f / DIM);
      float d0 = n0 - mu, d1 = n1 - mu, d2 = n2 - mu, d3 = n3 - mu;
      float var = wave_sum(d0*d0 + d1*d1 + d2*d2 + d3*d3) * (1.0f / DIM);
      float rs = rsqrtf(var + 1e-5f);
      bf16x4 ob;
      ob[0] = (bf16)(d0 * rs * gv.x + bv.x);
      ob[1] = (bf16)(d1 * rs * gv.y + bv.y);
      ob[2] = (bf16)(d2 * rs * gv.z + bv.z);
      ob[3] = (bf16)(d3 * rs * gv.w + bv.w);
      *reinterpret_cast<bf16x4*>(xn + (size_t)grow * 256 + lane * 4) = ob;
    }
  } else {
    float4 bo4 = reinterpret_cast<const float4*>(bo)[lane];
    for (int pass = 0; pass < 16; ++pass) {
      int grow = row0 + pass * 4 + wv;
      if (grow >= rows) continue;
      float x0 = bo4.x, x1 = bo4.y, x2 = bo4.z, x3 = bo4.w;
      float4 rv = reinterpret_cast<const float4*>(nodes + (size_t)grow * 256)[lane];
      float dot = x0 * wa.x + rv.x * wbv.x + x1 * wa.y + rv.y * wbv.y
                + x2 * wa.z + rv.z * wbv.z + x3 * wa.w + rv.w * wbv.w;
      dot = wave_sum(dot);
      float gate = 1.0f / (1.0f + __expf(-dot));
      float n0 = fmaf(x0 - rv.x, gate, rv.x);
      float n1 = fmaf(x1 - rv.y, gate, rv.y);
      float n2 = fmaf(x2 - rv.z, gate, rv.z);
      float n3 = fmaf(x3 - rv.w, gate, rv.w);
      float4 o; o.x = n0; o.y = n1; o.z = n2; o.w = n3;
      reinterpret_cast<float4*>(nodes + (size_t)grow * 256)[lane] = o;
      float mu = wave_sum(n0 + n1 + n2 + n3) * (1.0f / DIM);
      float d0 = n0 - mu, d1 = n1 - mu, d2 = n2 - mu, d3 = n3 - mu;
      float var = wave_sum(d0*d0 + d1*d1 + d2*d2 + d3*d3) * (1.0f / DIM);
      float rs = rsqrtf(var + 1e-5f);
      bf16x4 ob;
      ob[0] = (bf16)(d0 * rs * gv.x + bv.x);
      ob[1] = (bf16)(d1 * rs * gv.y + bv.y);
      ob[2] = (bf16)(d2 * rs * gv.z + bv.z);
      ob[3] = (bf16)(d3 * rs * gv.w + bv.w);
      *reinterpret_cast<bf16x4*>(xn + (size_t)grow * 256 + lane * 4) = ob;
    }
  }
}

// ---------------- fused FF + gr2 (+LN1next | +out-proj), 64-row panel --------
// 1x8 wave layout + double-buffered Hs (1 barrier/j) + cheap GELU + setprio.
// (512,2): LDS caps at 2 blocks/CU anyway; lift VGPR cap to 128 so the FULL-j
// W2 prefetch (pf2[8], both h2 halves) fits in registers (r15 was capped at 64
// and loaded the h2=1 half inside the MFMA cluster, exposing L2 latency).
template<int LAST>
__global__ __launch_bounds__(512, 2) void ff_fused(
    const bf16* __restrict__ A, const bf16* __restrict__ W1p,
    const float* __restrict__ b1, const bf16* __restrict__ W2p,
    const float* __restrict__ b2, float* __restrict__ nodes,
    const float* __restrict__ gff, const float* __restrict__ ln1g,
    const float* __restrict__ ln1b, bf16* __restrict__ A2,
    const float* __restrict__ Wout, const float* __restrict__ bout,
    float* __restrict__ out, int M) {
  __shared__ char smem[65536];
  bf16x8* Xs = (bf16x8*)smem;           // 32 KB (Cs aliases)
  bf16*   Cs = (bf16*)smem;
  bf16x8* Hs = (bf16x8*)(smem + 32768); // 2 x 16 KB (double-buffered)
  const int tid = threadIdx.x;
  const int lane = tid & 63, wv = tid >> 6;   // wv 0..7 = column group
  const int lm = lane & 15, kb = (lane >> 4) & 3;
  const int row0 = blockIdx.x * 64;
#pragma unroll
  for (int i = 0; i < 4; ++i) {
    int idx = tid + i * 512;
    int row = idx & 63, k8 = idx >> 6;
    int rga = row0 + row; if (rga >= M) rga = M - 1;
    Xs[idx] = *reinterpret_cast<const bf16x8*>(A + (size_t)rga * 256 + k8 * 8);
  }
  lds_barrier();
  const bf16x8* w1b = (const bf16x8*)W1p + kb * 128 + wv * 16 + lm;
  const bf16x8* w2b = (const bf16x8*)W2p + kb * 256 + wv * 32 + lm;
  f32x4 acc[4][2] = {};
  for (int j = 0; j < 8; ++j) {
    // FULL-j W2 prefetch: both h2 halves ride over FF1 + the barrier.
    bf16x8 pf2[8];
#pragma unroll
    for (int h2 = 0; h2 < 2; ++h2)
#pragma unroll
      for (int ks = 0; ks < 2; ++ks)
#pragma unroll
        for (int ni = 0; ni < 2; ++ni)
          pf2[h2 * 4 + ks * 2 + ni] =
              w2b[j * 4096 + h2 * 2048 + ks * 1024 + ni * 16];
    f32x4 acc1[4] = {};
    __builtin_amdgcn_s_setprio(1);
#pragma unroll
    for (int half = 0; half < 2; ++half) {
#pragma unroll
      for (int ks = 0; ks < 4; ++ks) {
        bf16x8 bfr = w1b[j * 4096 + half * 2048 + ks * 512];
        bf16x8 af[4];
#pragma unroll
        for (int mi = 0; mi < 4; ++mi)
          af[mi] = Xs[(half * 16 + ks * 4 + kb) * 64 + mi * 16 + lm];
#pragma unroll
        for (int mi = 0; mi < 4; ++mi)
          acc1[mi] = __builtin_amdgcn_mfma_f32_16x16x32_bf16(af[mi], bfr, acc1[mi], 0, 0, 0);
      }
    }
    __builtin_amdgcn_s_setprio(0);
    {
      bf16* hsb = (bf16*)(Hs + (j & 1) * 1024);
      int c = wv * 16 + lm;
      float bval = b1[j * 128 + c];
#pragma unroll
      for (int mi = 0; mi < 4; ++mi)
#pragma unroll
        for (int e = 0; e < 4; ++e) {
          int r = mi * 16 + kb * 4 + e;
          float v = fast_gelu(acc1[mi][e] + bval);
          hsb[((c >> 3) * 64 + r) * 8 + (c & 7)] = (bf16)v;
        }
    }
    lds_barrier();                    // Hs[j&1] visible; the ONLY barrier per j
    const bf16x8* hb = Hs + (j & 1) * 1024;
    __builtin_amdgcn_s_setprio(1);
#pragma unroll
    for (int h2 = 0; h2 < 2; ++h2) {
#pragma unroll
      for (int ks = 0; ks < 2; ++ks) {
        bf16x8 af[4];
#pragma unroll
        for (int mi = 0; mi < 4; ++mi)
          af[mi] = hb[(h2 * 8 + ks * 4 + kb) * 64 + mi * 16 + lm];
#pragma unroll
        for (int mi = 0; mi < 4; ++mi)
#pragma unroll
          for (int ni = 0; ni < 2; ++ni)
            acc[mi][ni] = __builtin_amdgcn_mfma_f32_16x16x32_bf16(
                af[mi], pf2[h2 * 4 + ks * 2 + ni], acc[mi][ni], 0, 0, 0);
      }
    }
    __builtin_amdgcn_s_setprio(0);
  }
  // Cs aliases Xs; barrier(7) guarantees all waves finished FF1(7)'s Xs reads.
#pragma unroll
  for (int ni = 0; ni < 2; ++ni) {
    int c = wv * 32 + ni * 16 + lm;
    float bval = b2[c];
#pragma unroll
    for (int mi = 0; mi < 4; ++mi)
#pragma unroll
      for (int e = 0; e < 4; ++e) {
        int r = mi * 16 + kb * 4 + e;
        int ch = (c >> 3) ^ (r & 7);
        Cs[r * 256 + ch * 8 + (c & 7)] = (bf16)(acc[mi][ni][e] + bval);
      }
  }
  // hoisted epilogue invariants (loads overlap the Cs pack)
  float4 w0 = reinterpret_cast<const float4*>(gff)[lane];
  float4 w1 = reinterpret_cast<const float4*>(gff + 256)[lane];
  float4 w2 = reinterpret_cast<const float4*>(gff + 512)[lane];
  float4 wa, wbv;
  wa.x = w0.x + w2.x; wa.y = w0.y + w2.y; wa.z = w0.z + w2.z; wa.w = w0.w + w2.w;
  wbv.x = w1.x - w2.x; wbv.y = w1.y - w2.y; wbv.z = w1.z - w2.z; wbv.w = w1.w - w2.w;
  float4 gv, bv, wo4;
  if (LAST) {
    wo4 = reinterpret_cast<const float4*>(Wout)[lane];
  } else {
    gv = reinterpret_cast<const float4*>(ln1g)[lane];
    bv = reinterpret_cast<const float4*>(ln1b)[lane];
  }
  lds_barrier();
  for (int pass = 0; pass < 8; ++pass) {
    int r = pass * 8 + wv;
    int grow = row0 + r;
    if (grow >= M) continue;
    int ch = (lane >> 1) ^ (r & 7);
    bf16x4 c4 = *reinterpret_cast<const bf16x4*>(Cs + r * 256 + ch * 8 + (lane & 1) * 4);
    float x0 = (float)c4[0], x1 = (float)c4[1], x2 = (float)c4[2], x3 = (float)c4[3];
    float4 rv = reinterpret_cast<const float4*>(nodes + (size_t)grow * 256)[lane];
    float dot = x0 * wa.x + rv.x * wbv.x + x1 * wa.y + rv.y * wbv.y
              + x2 * wa.z + rv.z * wbv.z + x3 * wa.w + rv.w * wbv.w;
    dot = wave_sum(dot);
    float gate = 1.0f / (1.0f + __expf(-dot));
    float n0 = fmaf(x0 - rv.x, gate, rv.x);
    float n1 = fmaf(x1 - rv.y, gate, rv.y);
    float n2 = fmaf(x2 - rv.z, gate, rv.z);
    float n3 = fmaf(x3 - rv.w, gate, rv.w);
    if (LAST) {
      float z = n0 * wo4.x + n1 * wo4.y + n2 * wo4.z + n3 * wo4.w;
      z = wave_sum(z);
      if (lane == 0) {
        z += bout[0];
        if (grow < HALF_N) {
          out[HALF_N + grow] = z;
        } else {
          int jj = grow - HALF_N;
          out[jj] = z;
          out[2 * HALF_N + jj] = z;
        }
      }
    } else {
      float4 o; o.x = n0; o.y = n1; o.z = n2; o.w = n3;
      reinterpret_cast<float4*>(nodes + (size_t)grow * 256)[lane] = o;
      if (grow < HALF_N) {
        float mu = wave_sum(n0 + n1 + n2 + n3) * (1.0f / DIM);
        float d0 = n0 - mu, d1 = n1 - mu, d2 = n2 - mu, d3 = n3 - mu;
        float var = wave_sum(d0*d0 + d1*d1 + d2*d2 + d3*d3) * (1.0f / DIM);
        float rs = rsqrtf(var + 1e-5f);
        bf16x4 ob;
        ob[0] = (bf16)(d0 * rs * gv.x + bv.x);
        ob[1] = (bf16)(d1 * rs * gv.y + bv.y);
        ob[2] = (bf16)(d2 * rs * gv.z + bv.z);
        ob[3] = (bf16)(d3 * rs * gv.w + bv.w);
        *reinterpret_cast<bf16x4*>(A2 + (size_t)grow * 512 + lane * 4) = ob;
      }
    }
  }
}

// ---------------- ELL build ----------------
__global__ void ell_build(const int* __restrict__ ei, int* __restrict__ deg,
                          int* __restrict__ ell) {
  int e = blockIdx.x * 256 + threadIdx.x;
  if (e >= N_EDGES) return;
  int s = ei[e], d = ei[N_EDGES + e];
  int pos = atomicAdd(&deg[d], 1);
  if (pos < MAXDEG) ell[d * MAXDEG + pos] = s;
}

// ---------------- attention gather (wave per dst, online softmax) ------------
__global__ void attn_gather(const int* __restrict__ deg, const int* __restrict__ ell,
                            const bf16* __restrict__ qkv, bf16* __restrict__ agg) {
  int d = blockIdx.x * 4 + (threadIdx.x >> 6);
  if (d >= HALF_N) return;
  int lane = threadIdx.x & 63;
  int cnt = deg[d]; if (cnt > MAXDEG) cnt = MAXDEG;
  const bf16* qr = qkv + (size_t)d * 768;
  bf16x4 qb = *reinterpret_cast<const bf16x4*>(qr + lane * 4);
  float q0 = (float)qb[0], q1 = (float)qb[1], q2 = (float)qb[2], q3 = (float)qb[3];
  float m = -INFINITY, den = 0.0f, a0 = 0.0f, a1 = 0.0f, a2 = 0.0f, a3 = 0.0f;
  int i = 0;
  for (; i + 2 <= cnt; i += 2) {
    int s0 = ell[d * MAXDEG + i];
    int s1 = ell[d * MAXDEG + i + 1];
    bf16x8 k0 = *reinterpret_cast<const bf16x8*>(qkv + (size_t)s0 * 768 + 256 + lane * 8);
    bf16x8 k1 = *reinterpret_cast<const bf16x8*>(qkv + (size_t)s1 * 768 + 256 + lane * 8);
    float p0 = q0 * (float)k0[0] + q1 * (float)k0[1] + q2 * (float)k0[2] + q3 * (float)k0[3];
    float p1 = q0 * (float)k1[0] + q1 * (float)k1[1] + q2 * (float)k1[2] + q3 * (float)k1[3];
    p0 += __shfl_xor(p0, 1); p1 += __shfl_xor(p1, 1);
    p0 += __shfl_xor(p0, 2); p1 += __shfl_xor(p1, 2);
    p0 += __shfl_xor(p0, 4); p1 += __shfl_xor(p1, 4);
    p0 += __shfl_xor(p0, 8); p1 += __shfl_xor(p1, 8);
    float s0v = p0 * 0.125f, s1v = p1 * 0.125f;
    float nm = fmaxf(m, fmaxf(s0v, s1v));
    float sc = __expf(m - nm);
    float w0 = __expf(s0v - nm), w1 = __expf(s1v - nm);
    den = den * sc + w0 + w1;
    a0 = a0 * sc + w0 * (float)k0[4] + w1 * (float)k1[4];
    a1 = a1 * sc + w0 * (float)k0[5] + w1 * (float)k1[5];
    a2 = a2 * sc + w0 * (float)k0[6] + w1 * (float)k1[6];
    a3 = a3 * sc + w0 * (float)k0[7] + w1 * (float)k1[7];
    m = nm;
  }
  if (i < cnt) {
    int s = ell[d * MAXDEG + i];
    bf16x8 kv8 = *reinterpret_cast<const bf16x8*>(qkv + (size_t)s * 768 + 256 + lane * 8);
    float p = q0 * (float)kv8[0] + q1 * (float)kv8[1] + q2 * (float)kv8[2] + q3 * (float)kv8[3];
    p += __shfl_xor(p, 1); p += __shfl_xor(p, 2);
    p += __shfl_xor(p, 4); p += __shfl_xor(p, 8);
    float sim = p * 0.125f;
    float nm = fmaxf(m, sim);
    float sc = __expf(m - nm);
    float w = __expf(sim - nm);
    den = den * sc + w;
    a0 = a0 * sc + w * (float)kv8[4];
    a1 = a1 * sc + w * (float)kv8[5];
    a2 = a2 * sc + w * (float)kv8[6];
    a3 = a3 * sc + w * (float)kv8[7];
    m = nm;
  }
  bf16x4 o;
  if (cnt > 0) {
    float inv = 1.0f / den;
    o[0] = (bf16)(a0 * inv);
    o[1] = (bf16)(a1 * inv);
    o[2] = (bf16)(a2 * inv);
    o[3] = (bf16)(a3 * inv);
  } else {
    o[0] = (bf16)0.0f; o[1] = (bf16)0.0f; o[2] = (bf16)0.0f; o[3] = (bf16)0.0f;
  }
  *reinterpret_cast<bf16x4*>(agg + (size_t)d * DIM + lane * 4) = o;
}

// ---------------- weight prep: chunk-packed bf16 layouts ----------------
__global__ void prep_w(const float* __restrict__ Wq, const float* __restrict__ Wkv,
                       const float* __restrict__ We, const float* __restrict__ Wo,
                       const float* __restrict__ W1, const float* __restrict__ W2,
                       bf16* __restrict__ wt) {
  int idx = blockIdx.x * 256 + threadIdx.x;
  if (idx >= 2 * WT_LAYER) return;
  int l = idx / WT_LAYER, r = idx % WT_LAYER;
  float v;
  if (r < 393216) {                       // qkv: 6 x [64 k8][128 n][8 e]
    int jn = r >> 16, t = r & 65535;
    int k8 = t >> 10, u = t & 1023, n = u >> 3, e = u & 7;
    int ncol = jn * 128 + n, k = k8 * 8 + e;
    if (ncol < 256) {
      v = (k < 256) ? Wq[l * 65536 + k * 256 + ncol] : 0.0f;
    } else {
      int u2 = ncol - 256;
      int c = (u2 >> 3) * 4 + (u2 & 3);
      int half = (u2 >> 2) & 1;
      if (k < 256) v = Wkv[l * 131072 + k * 512 + half * 256 + c];
      else         v = We[l * 131072 + (k - 256) * 256 + c];
    }
  } else if (r < 524288) {                // WO region: Wo part (k<256) only
    int rr = r - 393216;
    int jn = rr >> 16, t = rr & 65535;
    int k8 = t >> 10, u = t & 1023, n = u >> 3, e = u & 7;
    int k = k8 * 8 + e;
    if (k >= 256) return;                 // Weff part filled by prep_weff
    v = Wo[l * 65536 + k * 256 + jn * 128 + n];
  } else if (r < 786432) {                // W1: 8 x [32 k8][128 n][8 e]
    int rr = r - 524288;
    int j = rr >> 15, t = rr & 32767;
    int k8 = t >> 10, u = t & 1023, n = u >> 3, e = u & 7;
    v = W1[l * 262144 + (k8 * 8 + e) * 1024 + j * 128 + n];
  } else {                                // W2: 8 x [16 k8][256 n][8 e]
    int rr = r - 786432;
    int j = rr >> 15, t = rr & 32767;
    int k8 = t >> 11, u = t & 2047, n = u >> 3, e = u & 7;
    v = W2[l * 262144 + (j * 128 + k8 * 8 + e) * 256 + n];
  }
  wt[idx] = (bf16)v;
}

// Weff = We_bot @ Wo  (fp32 accumulate), packed into WO region k >= 256
__global__ void prep_weff(const float* __restrict__ We, const float* __restrict__ Wo,
                          bf16* __restrict__ wt) {
  int idx = blockIdx.x * 256 + threadIdx.x;
  if (idx >= 2 * 65536) return;
  int l = idx >> 16, r = idx & 65535;
  int k = r >> 8, n = r & 255;
  const float* wer = We + l * 131072 + (256 + k) * 256;
  const float* wor = Wo + l * 65536 + n;
  float acc = 0.0f;
#pragma unroll 4
  for (int m = 0; m < 256; ++m) acc += wer[m] * wor[m * 256];
  int kf = 256 + k;
  size_t off = (size_t)l * WT_LAYER + WT_WO +
               (n >> 7) * 65536 + (kf >> 3) * 1024 + (n & 127) * 8 + (kf & 7);
  wt[off] = (bf16)acc;
}

// bvec = be @ Wo + bo  -> biasq[1536 + l*256 + n]
__global__ void prep_bvec(const float* __restrict__ be, const float* __restrict__ Wo,
                          const float* __restrict__ bo, float* __restrict__ biasq) {
  int idx = blockIdx.x * 256 + threadIdx.x;
  if (idx >= 512) return;
  int l = idx >> 8, n = idx & 255;
  const float* ber = be + l * 256;
  const float* wor = Wo + l * 65536 + n;
  float acc = bo[l * 256 + n];
#pragma unroll 4
  for (int m = 0; m < 256; ++m) acc += ber[m] * wor[m * 256];
  biasq[1536 + l * 256 + n] = acc;
}

// qkv bias: [2][768] = [bq | interleaved bk/bv]
__global__ void prep_bias(const float* __restrict__ bq, const float* __restrict__ bkv,
                          float* __restrict__ biasq) {
  int i = blockIdx.x * 256 + threadIdx.x;
  if (i >= 1536) return;
  int l = i / 768, n = i % 768;
  float v;
  if (n < 256) v = bq[l * 256 + n];
  else {
    int u2 = n - 256;
    int c = (u2 >> 3) * 4 + (u2 & 3);
    int half = (u2 >> 2) & 1;
    v = bkv[l * 512 + half * 256 + c];
  }
  biasq[i] = v;
}

// x (fp32) -> A2 right half (bf16, stride 512)
__global__ void prep_x(const float* __restrict__ x, bf16* __restrict__ A2) {
  int i = blockIdx.x * 256 + threadIdx.x;
  if (i >= HALF_N * 64) return;
  int row = i >> 6, c = i & 63;
  float4 v = reinterpret_cast<const float4*>(x)[i];
  bf16x4 o;
  o[0] = (bf16)v.x; o[1] = (bf16)v.y; o[2] = (bf16)v.z; o[3] = (bf16)v.w;
  *reinterpret_cast<bf16x4*>(A2 + (size_t)row * 512 + 256 + c * 4) = o;
}

extern "C" void kernel_launch(void* const* d_in, const int* in_sizes, int n_in,
                              void* d_out, int out_size, void* d_ws, size_t ws_size,
                              hipStream_t stream) {
  const float* x     = (const float*)d_in[0];
  const int*   ei    = (const int*)d_in[1];
  const float* ln1_g = (const float*)d_in[2];
  const float* ln1_b = (const float*)d_in[3];
  const float* Wq    = (const float*)d_in[4];
  const float* bq    = (const float*)d_in[5];
  const float* Wkv   = (const float*)d_in[6];
  const float* bkv   = (const float*)d_in[7];
  const float* We    = (const float*)d_in[8];
  const float* be    = (const float*)d_in[9];
  const float* Wo    = (const float*)d_in[10];
  const float* bo    = (const float*)d_in[11];
  const float* g_attn= (const float*)d_in[12];
  const float* ln2_g = (const float*)d_in[13];
  const float* ln2_b = (const float*)d_in[14];
  const float* W1    = (const float*)d_in[15];
  const float* b1    = (const float*)d_in[16];
  const float* W2    = (const float*)d_in[17];
  const float* b2    = (const float*)d_in[18];
  const float* g_ff  = (const float*)d_in[19];
  const float* Wout  = (const float*)d_in[20];
  const float* bout  = (const float*)d_in[21];
  float* out = (float*)d_out;

  char* base = (char*)d_ws;
  float* nodes   = (float*)base;  base += (size_t)N_NODES * DIM * 4;      // 51.2 MB
  bf16*  A2      = (bf16*)base;   base += (size_t)HALF_N * 512 * 2;       // 25.6 MB
  bf16*  xn_bf   = (bf16*)base;   base += (size_t)N_NODES * DIM * 2;      // 25.6 MB
  bf16*  qkv     = (bf16*)base;   base += (size_t)HALF_N * 768 * 2;       // 38.4 MB
  bf16*  agg     = (bf16*)base;   base += (size_t)HALF_N * DIM * 2;       // 12.8 MB
  bf16*  wt      = (bf16*)base;   base += (size_t)2 * WT_LAYER * 2;       // 4.2 MB
  float* biasq   = (float*)base;  base += 2048 * 4;
  int*   deg     = (int*)base;    base += HALF_N * 4;
  int*   ell     = (int*)base;    base += (size_t)HALF_N * MAXDEG * 4;    // 6.4 MB

  // one-time prep
  hipMemcpyAsync(nodes, x, (size_t)N_NODES * DIM * sizeof(float),
                 hipMemcpyDeviceToDevice, stream);
  prep_w<<<(2 * WT_LAYER + 255) / 256, 256, 0, stream>>>(Wq, Wkv, We, Wo, W1, W2, wt);
  prep_weff<<<(2 * 65536 + 255) / 256, 256, 0, stream>>>(We, Wo, wt);
  prep_bvec<<<2, 256, 0, stream>>>(be, Wo, bo, biasq);
  prep_bias<<<6, 256, 0, stream>>>(bq, bkv, biasq);
  prep_x<<<(HALF_N * 64 + 255) / 256, 256, 0, stream>>>(x, A2);
  hipMemsetAsync(deg, 0, HALF_N * sizeof(int), stream);
  ell_build<<<(N_EDGES + 255) / 256, 256, 0, stream>>>(ei, deg, ell);

  const int GP_H = (HALF_N + 63) / 64;    // 391
  const int GP_N = (N_NODES + 63) / 64;   // 782

  for (int l = 0; l < NDEPTH; ++l) {
    const bf16* wl = wt + (size_t)l * WT_LAYER;
    if (l == 0)
      ln0_kernel<<<(HALF_N + 3) / 4, 256, 0, stream>>>(x, ln1_g, ln1_b, A2);
    // qkv = [xn|x] @ qkvT + bias (k/v interleaved cols, N=768)
    gemm_nloop<512, 6><<<GP_H, 512, 0, stream>>>(A2, wl + WT_QKVE, biasq + l * 768, qkv, HALF_N);
    // attention gather (softV only; eB folded via Weff)
    attn_gather<<<(HALF_N + 3) / 4, 256, 0, stream>>>(deg, ell, qkv, agg);
    // attn_out = [agg|x] @ [Wo;Weff] + bvec, fused gr1 + LN2 (ALL rows)
    wo_fused<<<GP_N, 256, 0, stream>>>(agg, A2, wl + WT_WO, biasq + 1536 + l * 256,
                                       bo + l * DIM, deg, g_attn + l * 768,
                                       ln2_g + l * DIM, ln2_b + l * DIM,
                                       nodes, xn_bf, N_NODES);
    // fused FF + gr2 (+LN1next into A2 | +out-proj)
    if (l < NDEPTH - 1) {
      ff_fused<0><<<GP_N, 512, 0, stream>>>(
          xn_bf, wl + WT_W1, b1 + l * 1024, wl + WT_W2, b2 + l * DIM,
          nodes, g_ff + l * 768, ln1_g + (l + 1) * DIM, ln1_b + (l + 1) * DIM, A2,
          nullptr, nullptr, nullptr, N_NODES);
    } else {
      ff_fused<1><<<GP_N, 512, 0, stream>>>(
          xn_bf, wl + WT_W1, b1 + l * 1024, wl + WT_W2, b2 + l * DIM,
          nodes, g_ff + l * 768, nullptr, nullptr, nullptr,
          Wout, bout, out, N_NODES);
    }
  }
}

// Round 17
// 459.075 us; speedup vs baseline: 1.0567x; 1.0567x over previous
//
#include <hip/hip_runtime.h>
#include <cmath>

#define N_NODES 50000
#define N_EDGES 100000
#define HALF_N  25000
#define DIM     256
#define NDEPTH  2
#define MAXDEG  64

// per-layer weight-buffer offsets (bf16 elements), chunk-packed layouts
#define WT_QKVE 0          // 6 tiles x [64 k8][128 n] bf16x8 (q | k/v interleaved)
#define WT_WO   393216     // 2 tiles x [64 k8][128 n]  K=512: [Wo ; Weff]
#define WT_W1   524288     // 8 chunks x [32 k8][128 n]
#define WT_W2   786432     // 8 chunks x [16 k8][256 n]
#define WT_LAYER 1048576

typedef __bf16 bf16;
typedef bf16 bf16x8 __attribute__((ext_vector_type(8)));
typedef bf16 bf16x4 __attribute__((ext_vector_type(4)));
typedef float f32x4 __attribute__((ext_vector_type(4)));

// LDS-only barrier: does NOT drain vmcnt (global loads stay in flight).
__device__ __forceinline__ void lds_barrier() {
  asm volatile("s_waitcnt lgkmcnt(0)" ::: "memory");
  __builtin_amdgcn_s_barrier();
  __builtin_amdgcn_sched_barrier(0);
}

__device__ __forceinline__ float wave_sum(float v) {
  v += __shfl_xor(v, 1);
  v += __shfl_xor(v, 2);
  v += __shfl_xor(v, 4);
  v += __shfl_xor(v, 8);
  v += __shfl_xor(v, 16);
  v += __shfl_xor(v, 32);
  return v;
}

// 7-op GELU: x * sigmoid(1.59577*(x + 0.044715 x^3)) via single exp2.
__device__ __forceinline__ float fast_gelu(float x) {
  float p = x * x;
  float q = fmaf(p, -0.10294437f, -2.3022112f);
  float e = exp2f(x * q);
  return x * __builtin_amdgcn_rcpf(1.0f + e);
}

// ---------------- layer-0 LN1: x -> A2 left half (stride 512) ----------------
__global__ void ln0_kernel(const float* __restrict__ in, const float* __restrict__ g,
                           const float* __restrict__ b, bf16* __restrict__ A2) {
  int row = blockIdx.x * 4 + (threadIdx.x >> 6);
  if (row >= HALF_N) return;
  int lane = threadIdx.x & 63;
  float4 x = reinterpret_cast<const float4*>(in + (size_t)row * DIM)[lane];
  float mu = wave_sum(x.x + x.y + x.z + x.w) * (1.0f / DIM);
  float d0 = x.x - mu, d1 = x.y - mu, d2 = x.z - mu, d3 = x.w - mu;
  float var = wave_sum(d0*d0 + d1*d1 + d2*d2 + d3*d3) * (1.0f / DIM);
  float r = rsqrtf(var + 1e-5f);
  float4 gv = reinterpret_cast<const float4*>(g)[lane];
  float4 bv = reinterpret_cast<const float4*>(b)[lane];
  bf16x4 o;
  o[0] = (bf16)(d0 * r * gv.x + bv.x);
  o[1] = (bf16)(d1 * r * gv.y + bv.y);
  o[2] = (bf16)(d2 * r * gv.z + bv.z);
  o[3] = (bf16)(d3 * r * gv.w + bv.w);
  *reinterpret_cast<bf16x4*>(A2 + (size_t)row * 512 + lane * 4) = o;
}

// ---------------- N-loop MFMA GEMM (qkv): 512 threads, 8 waves, ni=1 ---------
template<int KK, int NJ>
__global__ __launch_bounds__(512, 2) void gemm_nloop(
    const bf16* __restrict__ A, const bf16* __restrict__ Wp,
    const float* __restrict__ bias, bf16* __restrict__ C, int M) {
  constexpr int STEPS = KK / 64;
  __shared__ bf16x8 As[KK * 8];        // KK=512 -> 64 KB
  __shared__ bf16 Cs[64 * 128];        // 16 KB
  const int tid = threadIdx.x;
  const int lane = tid & 63, wv = tid >> 6;
  const int lm = lane & 15, kb = (lane >> 4) & 3;
  const int row0 = blockIdx.x * 64;
#pragma unroll
  for (int i = 0; i < KK / 64; ++i) {
    int idx = tid + i * 512;
    int row = idx & 63, k8 = idx >> 6;
    int rga = row0 + row; if (rga >= M) rga = M - 1;
    As[idx] = *reinterpret_cast<const bf16x8*>(A + (size_t)rga * KK + k8 * 8);
  }
  const bf16x8* wb = reinterpret_cast<const bf16x8*>(Wp) + kb * 128 + wv * 16 + lm;
  bf16x8 pfr = wb[0];
  lds_barrier();
  for (int jn = 0; jn < NJ; ++jn) {
    f32x4 acc[4] = {};
    __builtin_amdgcn_s_setprio(1);
#pragma unroll
    for (int st = 0; st < STEPS; ++st) {
#pragma unroll
      for (int ks = 0; ks < 2; ++ks) {
        bf16x8 bfr = (st == 0 && ks == 0)
                   ? pfr
                   : wb[(size_t)jn * (KK * 16) + st * 1024 + ks * 512];
        bf16x8 af[4];
#pragma unroll
        for (int mi = 0; mi < 4; ++mi)
          af[mi] = As[(st * 8 + ks * 4 + kb) * 64 + mi * 16 + lm];
#pragma unroll
        for (int mi = 0; mi < 4; ++mi)
          acc[mi] = __builtin_amdgcn_mfma_f32_16x16x32_bf16(af[mi], bfr, acc[mi], 0, 0, 0);
      }
    }
    __builtin_amdgcn_s_setprio(0);
    if (jn + 1 < NJ) pfr = wb[(size_t)(jn + 1) * (KK * 16)];
    lds_barrier();
    {
      int c = wv * 16 + lm;
      float bval = bias[jn * 128 + c];
#pragma unroll
      for (int mi = 0; mi < 4; ++mi)
#pragma unroll
        for (int e = 0; e < 4; ++e) {
          int r = mi * 16 + kb * 4 + e;
          Cs[r * 128 + c] = (bf16)(acc[mi][e] + bval);
        }
    }
    lds_barrier();
    bf16x8* C8 = reinterpret_cast<bf16x8*>(C);
    const bf16x8* Cs8 = (const bf16x8*)Cs;
#pragma unroll
    for (int i = 0; i < 2; ++i) {
      int idx = tid + i * 512;
      int row = idx >> 4, c8 = idx & 15;
      int grow = row0 + row;
      if (grow < M) C8[(size_t)grow * (NJ * 16) + jn * 16 + c8] = Cs8[row * 16 + c8];
    }
  }
}

// ---------------- Wo GEMM (K=512: [agg|x] @ [Wo;Weff]) + gr1 + LN2 ----------
__global__ __launch_bounds__(256, 2) void wo_fused(
    const bf16* __restrict__ agg, const bf16* __restrict__ A2,
    const bf16* __restrict__ Wp, const float* __restrict__ bvec,
    const float* __restrict__ bo, const int* __restrict__ deg,
    const float* __restrict__ gattn, const float* __restrict__ ln2g,
    const float* __restrict__ ln2b, float* __restrict__ nodes,
    bf16* __restrict__ xn, int rows) {
  __shared__ bf16x8 As[2048];          // agg tile [32 k8][64 row] 32 KB
  __shared__ bf16 Cs[64 * 256];        // 32 KB, XOR-swizzled chunks
  const int tid = threadIdx.x;
  const int lane = tid & 63, wv = tid >> 6;
  const int row0 = blockIdx.x * 64;
  float4 w0 = reinterpret_cast<const float4*>(gattn)[lane];
  float4 w1 = reinterpret_cast<const float4*>(gattn + 256)[lane];
  float4 w2 = reinterpret_cast<const float4*>(gattn + 512)[lane];
  float4 wa, wbv;
  wa.x = w0.x + w2.x; wa.y = w0.y + w2.y; wa.z = w0.z + w2.z; wa.w = w0.w + w2.w;
  wbv.x = w1.x - w2.x; wbv.y = w1.y - w2.y; wbv.z = w1.z - w2.z; wbv.w = w1.w - w2.w;
  float4 gv = reinterpret_cast<const float4*>(ln2g)[lane];
  float4 bv = reinterpret_cast<const float4*>(ln2b)[lane];
  if (row0 < HALF_N) {
    const int wr = wv >> 1, wc = wv & 1;
    const int lm = lane & 15, kb = (lane >> 4) & 3;
#pragma unroll
    for (int i = 0; i < 8; ++i) {
      int idx = tid + i * 256;
      int row = idx & 63, k8 = idx >> 6;
      int rga = row0 + row; if (rga >= HALF_N) rga = HALF_N - 1;
      As[idx] = *reinterpret_cast<const bf16x8*>(agg + (size_t)rga * 256 + k8 * 8);
    }
    bf16x8 afx[2][8];
#pragma unroll
    for (int mi = 0; mi < 2; ++mi) {
      int row = row0 + wr * 32 + mi * 16 + lm;
      if (row >= HALF_N) row = HALF_N - 1;
      const bf16* pa = A2 + (size_t)row * 512 + 256 + kb * 8;
#pragma unroll
      for (int t = 0; t < 8; ++t)
        afx[mi][t] = *reinterpret_cast<const bf16x8*>(pa + t * 32);
    }
    lds_barrier();
    const bf16x8* wb = reinterpret_cast<const bf16x8*>(Wp) + kb * 128 + wc * 64 + lm;
    for (int jn = 0; jn < 2; ++jn) {
      f32x4 acc[2][4] = {};
      __builtin_amdgcn_s_setprio(1);
#pragma unroll
      for (int st = 0; st < 8; ++st) {
#pragma unroll
        for (int ks = 0; ks < 2; ++ks) {
          bf16x8 bfr[4], af[2];
#pragma unroll
          for (int ni = 0; ni < 4; ++ni)
            bfr[ni] = wb[jn * 8192 + (st * 8 + ks * 4) * 128 + ni * 16];
#pragma unroll
          for (int mi = 0; mi < 2; ++mi)
            af[mi] = (st < 4) ? As[(st * 8 + ks * 4 + kb) * 64 + wr * 32 + mi * 16 + lm]
                              : afx[mi][(st - 4) * 2 + ks];
#pragma unroll
          for (int mi = 0; mi < 2; ++mi)
#pragma unroll
            for (int ni = 0; ni < 4; ++ni)
              acc[mi][ni] = __builtin_amdgcn_mfma_f32_16x16x32_bf16(af[mi], bfr[ni], acc[mi][ni], 0, 0, 0);
        }
      }
      __builtin_amdgcn_s_setprio(0);
#pragma unroll
      for (int ni = 0; ni < 4; ++ni) {
        int cfull = jn * 128 + wc * 64 + ni * 16 + lm;
        float bval = bvec[cfull];
#pragma unroll
        for (int mi = 0; mi < 2; ++mi)
#pragma unroll
          for (int e = 0; e < 4; ++e) {
            int r = wr * 32 + mi * 16 + kb * 4 + e;
            int ch = (cfull >> 3) ^ (r & 7);
            Cs[r * 256 + ch * 8 + (cfull & 7)] = (bf16)(acc[mi][ni][e] + bval);
          }
      }
    }
    lds_barrier();
    for (int pass = 0; pass < 16; ++pass) {
      int r = pass * 4 + wv;
      int grow = row0 + r;
      float x0, x1, x2, x3;
      if (grow >= HALF_N || deg[grow] == 0) {
        float4 bo4 = reinterpret_cast<const float4*>(bo)[lane];
        x0 = bo4.x; x1 = bo4.y; x2 = bo4.z; x3 = bo4.w;
      } else {
        int ch = (lane >> 1) ^ (r & 7);
        bf16x4 c4 = *reinterpret_cast<const bf16x4*>(Cs + r * 256 + ch * 8 + (lane & 1) * 4);
        x0 = (float)c4[0]; x1 = (float)c4[1]; x2 = (float)c4[2]; x3 = (float)c4[3];
      }
      float4 rv = reinterpret_cast<const float4*>(nodes + (size_t)grow * 256)[lane];
      float dot = x0 * wa.x + rv.x * wbv.x + x1 * wa.y + rv.y * wbv.y
                + x2 * wa.z + rv.z * wbv.z + x3 * wa.w + rv.w * wbv.w;
      dot = wave_sum(dot);
      float gate = 1.0f / (1.0f + __expf(-dot));
      float n0 = fmaf(x0 - rv.x, gate, rv.x);
      float n1 = fmaf(x1 - rv.y, gate, rv.y);
      float n2 = fmaf(x2 - rv.z, gate, rv.z);
      float n3 = fmaf(x3 - rv.w, gate, rv.w);
      float4 o; o.x = n0; o.y = n1; o.z = n2; o.w = n3;
      reinterpret_cast<float4*>(nodes + (size_t)grow * 256)[lane] = o;
      float mu = wave_sum(n0 + n1 + n2 + n3) * (1.0f / DIM);
      float d0 = n0 - mu, d1 = n1 - mu, d2 = n2 - mu, d3 = n3 - mu;
      float var = wave_sum(d0*d0 + d1*d1 + d2*d2 + d3*d3) * (1.0f / DIM);
      float rs = rsqrtf(var + 1e-5f);
      bf16x4 ob;
      ob[0] = (bf16)(d0 * rs * gv.x + bv.x);
      ob[1] = (bf16)(d1 * rs * gv.y + bv.y);
      ob[2] = (bf16)(d2 * rs * gv.z + bv.z);
      ob[3] = (bf16)(d3 * rs * gv.w + bv.w);
      *reinterpret_cast<bf16x4*>(xn + (size_t)grow * 256 + lane * 4) = ob;
    }
  } else {
    float4 bo4 = reinterpret_cast<const float4*>(bo)[lane];
    for (int pass = 0; pass < 16; ++pass) {
      int grow = row0 + pass * 4 + wv;
      if (grow >= rows) continue;
      float x0 = bo4.x, x1 = bo4.y, x2 = bo4.z, x3 = bo4.w;
      float4 rv = reinterpret_cast<const float4*>(nodes + (size_t)grow * 256)[lane];
      float dot = x0 * wa.x + rv.x * wbv.x + x1 * wa.y + rv.y * wbv.y
                + x2 * wa.z + rv.z * wbv.z + x3 * wa.w + rv.w * wbv.w;
      dot = wave_sum(dot);
      float gate = 1.0f / (1.0f + __expf(-dot));
      float n0 = fmaf(x0 - rv.x, gate, rv.x);
      float n1 = fmaf(x1 - rv.y, gate, rv.y);
      float n2 = fmaf(x2 - rv.z, gate, rv.z);
      float n3 = fmaf(x3 - rv.w, gate, rv.w);
      float4 o; o.x = n0; o.y = n1; o.z = n2; o.w = n3;
      reinterpret_cast<float4*>(nodes + (size_t)grow * 256)[lane] = o;
      float mu = wave_sum(n0 + n1 + n2 + n3) * (1.0f / DIM);
      float d0 = n0 - mu, d1 = n1 - mu, d2 = n2 - mu, d3 = n3 - mu;
      float var = wave_sum(d0*d0 + d1*d1 + d2*d2 + d3*d3) * (1.0f / DIM);
      float rs = rsqrtf(var + 1e-5f);
      bf16x4 ob;
      ob[0] = (bf16)(d0 * rs * gv.x + bv.x);
      ob[1] = (bf16)(d1 * rs * gv.y + bv.y);
      ob[2] = (bf16)(d2 * rs * gv.z + bv.z);
      ob[3] = (bf16)(d3 * rs * gv.w + bv.w);
      *reinterpret_cast<bf16x4*>(xn + (size_t)grow * 256 + lane * 4) = ob;
    }
  }
}

// ---------------- fused FF + gr2 (+LN1next | +out-proj), 64-row panel --------
// 1x8 wave layout + double-buffered Hs (1 barrier/j) + cheap GELU + setprio.
template<int LAST>
__global__ __launch_bounds__(512, 3) void ff_fused(
    const bf16* __restrict__ A, const bf16* __restrict__ W1p,
    const float* __restrict__ b1, const bf16* __restrict__ W2p,
    const float* __restrict__ b2, float* __restrict__ nodes,
    const float* __restrict__ gff, const float* __restrict__ ln1g,
    const float* __restrict__ ln1b, bf16* __restrict__ A2,
    const float* __restrict__ Wout, const float* __restrict__ bout,
    float* __restrict__ out, int M) {
  __shared__ char smem[65536];
  bf16x8* Xs = (bf16x8*)smem;           // 32 KB (Cs aliases)
  bf16*   Cs = (bf16*)smem;
  bf16x8* Hs = (bf16x8*)(smem + 32768); // 2 x 16 KB (double-buffered)
  const int tid = threadIdx.x;
  const int lane = tid & 63, wv = tid >> 6;   // wv 0..7 = column group
  const int lm = lane & 15, kb = (lane >> 4) & 3;
  const int row0 = blockIdx.x * 64;
#pragma unroll
  for (int i = 0; i < 4; ++i) {
    int idx = tid + i * 512;
    int row = idx & 63, k8 = idx >> 6;
    int rga = row0 + row; if (rga >= M) rga = M - 1;
    Xs[idx] = *reinterpret_cast<const bf16x8*>(A + (size_t)rga * 256 + k8 * 8);
  }
  lds_barrier();
  const bf16x8* w1b = (const bf16x8*)W1p + kb * 128 + wv * 16 + lm;
  const bf16x8* w2b = (const bf16x8*)W2p + kb * 256 + wv * 32 + lm;
  f32x4 acc[4][2] = {};
  for (int j = 0; j < 8; ++j) {
    bf16x8 pf2[4];
#pragma unroll
    for (int ks = 0; ks < 2; ++ks)
#pragma unroll
      for (int ni = 0; ni < 2; ++ni)
        pf2[ks * 2 + ni] = w2b[j * 4096 + ks * 1024 + ni * 16];
    f32x4 acc1[4] = {};
    __builtin_amdgcn_s_setprio(1);
#pragma unroll
    for (int half = 0; half < 2; ++half) {
#pragma unroll
      for (int ks = 0; ks < 4; ++ks) {
        bf16x8 bfr = w1b[j * 4096 + half * 2048 + ks * 512];
        bf16x8 af[4];
#pragma unroll
        for (int mi = 0; mi < 4; ++mi)
          af[mi] = Xs[(half * 16 + ks * 4 + kb) * 64 + mi * 16 + lm];
#pragma unroll
        for (int mi = 0; mi < 4; ++mi)
          acc1[mi] = __builtin_amdgcn_mfma_f32_16x16x32_bf16(af[mi], bfr, acc1[mi], 0, 0, 0);
      }
    }
    __builtin_amdgcn_s_setprio(0);
    {
      bf16* hsb = (bf16*)(Hs + (j & 1) * 1024);
      int c = wv * 16 + lm;
      float bval = b1[j * 128 + c];
#pragma unroll
      for (int mi = 0; mi < 4; ++mi)
#pragma unroll
        for (int e = 0; e < 4; ++e) {
          int r = mi * 16 + kb * 4 + e;
          float v = fast_gelu(acc1[mi][e] + bval);
          hsb[((c >> 3) * 64 + r) * 8 + (c & 7)] = (bf16)v;
        }
    }
    lds_barrier();                    // Hs[j&1] visible; the ONLY barrier per j
    const bf16x8* hb = Hs + (j & 1) * 1024;
    __builtin_amdgcn_s_setprio(1);
#pragma unroll
    for (int h2 = 0; h2 < 2; ++h2) {
#pragma unroll
      for (int ks = 0; ks < 2; ++ks) {
        bf16x8 bfr[2], af[4];
#pragma unroll
        for (int ni = 0; ni < 2; ++ni)
          bfr[ni] = (h2 == 0) ? pf2[ks * 2 + ni]
                              : w2b[j * 4096 + 2048 + ks * 1024 + ni * 16];
#pragma unroll
        for (int mi = 0; mi < 4; ++mi)
          af[mi] = hb[(h2 * 8 + ks * 4 + kb) * 64 + mi * 16 + lm];
#pragma unroll
        for (int mi = 0; mi < 4; ++mi)
#pragma unroll
          for (int ni = 0; ni < 2; ++ni)
            acc[mi][ni] = __builtin_amdgcn_mfma_f32_16x16x32_bf16(af[mi], bfr[ni], acc[mi][ni], 0, 0, 0);
      }
    }
    __builtin_amdgcn_s_setprio(0);
  }
  // Cs aliases Xs; barrier(7) guarantees all waves finished FF1(7)'s Xs reads.
#pragma unroll
  for (int ni = 0; ni < 2; ++ni) {
    int c = wv * 32 + ni * 16 + lm;
    float bval = b2[c];
#pragma unroll
    for (int mi = 0; mi < 4; ++mi)
#pragma unroll
      for (int e = 0; e < 4; ++e) {
        int r = mi * 16 + kb * 4 + e;
        int ch = (c >> 3) ^ (r & 7);
        Cs[r * 256 + ch * 8 + (c & 7)] = (bf16)(acc[mi][ni][e] + bval);
      }
  }
  // hoisted epilogue invariants (loads overlap the Cs pack)
  float4 w0 = reinterpret_cast<const float4*>(gff)[lane];
  float4 w1 = reinterpret_cast<const float4*>(gff + 256)[lane];
  float4 w2 = reinterpret_cast<const float4*>(gff + 512)[lane];
  float4 wa, wbv;
  wa.x = w0.x + w2.x; wa.y = w0.y + w2.y; wa.z = w0.z + w2.z; wa.w = w0.w + w2.w;
  wbv.x = w1.x - w2.x; wbv.y = w1.y - w2.y; wbv.z = w1.z - w2.z; wbv.w = w1.w - w2.w;
  float4 gv, bv, wo4;
  if (LAST) {
    wo4 = reinterpret_cast<const float4*>(Wout)[lane];
  } else {
    gv = reinterpret_cast<const float4*>(ln1g)[lane];
    bv = reinterpret_cast<const float4*>(ln1b)[lane];
  }
  lds_barrier();
  for (int pass = 0; pass < 8; ++pass) {
    int r = pass * 8 + wv;
    int grow = row0 + r;
    if (grow >= M) continue;
    int ch = (lane >> 1) ^ (r & 7);
    bf16x4 c4 = *reinterpret_cast<const bf16x4*>(Cs + r * 256 + ch * 8 + (lane & 1) * 4);
    float x0 = (float)c4[0], x1 = (float)c4[1], x2 = (float)c4[2], x3 = (float)c4[3];
    float4 rv = reinterpret_cast<const float4*>(nodes + (size_t)grow * 256)[lane];
    float dot = x0 * wa.x + rv.x * wbv.x + x1 * wa.y + rv.y * wbv.y
              + x2 * wa.z + rv.z * wbv.z + x3 * wa.w + rv.w * wbv.w;
    dot = wave_sum(dot);
    float gate = 1.0f / (1.0f + __expf(-dot));
    float n0 = fmaf(x0 - rv.x, gate, rv.x);
    float n1 = fmaf(x1 - rv.y, gate, rv.y);
    float n2 = fmaf(x2 - rv.z, gate, rv.z);
    float n3 = fmaf(x3 - rv.w, gate, rv.w);
    if (LAST) {
      float z = n0 * wo4.x + n1 * wo4.y + n2 * wo4.z + n3 * wo4.w;
      z = wave_sum(z);
      if (lane == 0) {
        z += bout[0];
        if (grow < HALF_N) {
          out[HALF_N + grow] = z;
        } else {
          int jj = grow - HALF_N;
          out[jj] = z;
          out[2 * HALF_N + jj] = z;
        }
      }
    } else {
      float4 o; o.x = n0; o.y = n1; o.z = n2; o.w = n3;
      reinterpret_cast<float4*>(nodes + (size_t)grow * 256)[lane] = o;
      if (grow < HALF_N) {
        float mu = wave_sum(n0 + n1 + n2 + n3) * (1.0f / DIM);
        float d0 = n0 - mu, d1 = n1 - mu, d2 = n2 - mu, d3 = n3 - mu;
        float var = wave_sum(d0*d0 + d1*d1 + d2*d2 + d3*d3) * (1.0f / DIM);
        float rs = rsqrtf(var + 1e-5f);
        bf16x4 ob;
        ob[0] = (bf16)(d0 * rs * gv.x + bv.x);
        ob[1] = (bf16)(d1 * rs * gv.y + bv.y);
        ob[2] = (bf16)(d2 * rs * gv.z + bv.z);
        ob[3] = (bf16)(d3 * rs * gv.w + bv.w);
        *reinterpret_cast<bf16x4*>(A2 + (size_t)grow * 512 + lane * 4) = ob;
      }
    }
  }
}

// ---------------- ELL build ----------------
__global__ void ell_build(const int* __restrict__ ei, int* __restrict__ deg,
                          int* __restrict__ ell) {
  int e = blockIdx.x * 256 + threadIdx.x;
  if (e >= N_EDGES) return;
  int s = ei[e], d = ei[N_EDGES + e];
  int pos = atomicAdd(&deg[d], 1);
  if (pos < MAXDEG) ell[d * MAXDEG + pos] = s;
}

// ---------------- attention gather (wave per dst, online softmax) ------------
__global__ void attn_gather(const int* __restrict__ deg, const int* __restrict__ ell,
                            const bf16* __restrict__ qkv, bf16* __restrict__ agg) {
  int d = blockIdx.x * 4 + (threadIdx.x >> 6);
  if (d >= HALF_N) return;
  int lane = threadIdx.x & 63;
  int cnt = deg[d]; if (cnt > MAXDEG) cnt = MAXDEG;
  const bf16* qr = qkv + (size_t)d * 768;
  bf16x4 qb = *reinterpret_cast<const bf16x4*>(qr + lane * 4);
  float q0 = (float)qb[0], q1 = (float)qb[1], q2 = (float)qb[2], q3 = (float)qb[3];
  float m = -INFINITY, den = 0.0f, a0 = 0.0f, a1 = 0.0f, a2 = 0.0f, a3 = 0.0f;
  int i = 0;
  for (; i + 2 <= cnt; i += 2) {
    int s0 = ell[d * MAXDEG + i];
    int s1 = ell[d * MAXDEG + i + 1];
    bf16x8 k0 = *reinterpret_cast<const bf16x8*>(qkv + (size_t)s0 * 768 + 256 + lane * 8);
    bf16x8 k1 = *reinterpret_cast<const bf16x8*>(qkv + (size_t)s1 * 768 + 256 + lane * 8);
    float p0 = q0 * (float)k0[0] + q1 * (float)k0[1] + q2 * (float)k0[2] + q3 * (float)k0[3];
    float p1 = q0 * (float)k1[0] + q1 * (float)k1[1] + q2 * (float)k1[2] + q3 * (float)k1[3];
    p0 += __shfl_xor(p0, 1); p1 += __shfl_xor(p1, 1);
    p0 += __shfl_xor(p0, 2); p1 += __shfl_xor(p1, 2);
    p0 += __shfl_xor(p0, 4); p1 += __shfl_xor(p1, 4);
    p0 += __shfl_xor(p0, 8); p1 += __shfl_xor(p1, 8);
    float s0v = p0 * 0.125f, s1v = p1 * 0.125f;
    float nm = fmaxf(m, fmaxf(s0v, s1v));
    float sc = __expf(m - nm);
    float w0 = __expf(s0v - nm), w1 = __expf(s1v - nm);
    den = den * sc + w0 + w1;
    a0 = a0 * sc + w0 * (float)k0[4] + w1 * (float)k1[4];
    a1 = a1 * sc + w0 * (float)k0[5] + w1 * (float)k1[5];
    a2 = a2 * sc + w0 * (float)k0[6] + w1 * (float)k1[6];
    a3 = a3 * sc + w0 * (float)k0[7] + w1 * (float)k1[7];
    m = nm;
  }
  if (i < cnt) {
    int s = ell[d * MAXDEG + i];
    bf16x8 kv8 = *reinterpret_cast<const bf16x8*>(qkv + (size_t)s * 768 + 256 + lane * 8);
    float p = q0 * (float)kv8[0] + q1 * (float)kv8[1] + q2 * (float)kv8[2] + q3 * (float)kv8[3];
    p += __shfl_xor(p, 1); p += __shfl_xor(p, 2);
    p += __shfl_xor(p, 4); p += __shfl_xor(p, 8);
    float sim = p * 0.125f;
    float nm = fmaxf(m, sim);
    float sc = __expf(m - nm);
    float w = __expf(sim - nm);
    den = den * sc + w;
    a0 = a0 * sc + w * (float)kv8[4];
    a1 = a1 * sc + w * (float)kv8[5];
    a2 = a2 * sc + w * (float)kv8[6];
    a3 = a3 * sc + w * (float)kv8[7];
    m = nm;
  }
  bf16x4 o;
  if (cnt > 0) {
    float inv = 1.0f / den;
    o[0] = (bf16)(a0 * inv);
    o[1] = (bf16)(a1 * inv);
    o[2] = (bf16)(a2 * inv);
    o[3] = (bf16)(a3 * inv);
  } else {
    o[0] = (bf16)0.0f; o[1] = (bf16)0.0f; o[2] = (bf16)0.0f; o[3] = (bf16)0.0f;
  }
  *reinterpret_cast<bf16x4*>(agg + (size_t)d * DIM + lane * 4) = o;
}

// ---------------- weight prep: chunk-packed bf16 layouts ----------------
__global__ void prep_w(const float* __restrict__ Wq, const float* __restrict__ Wkv,
                       const float* __restrict__ We, const float* __restrict__ Wo,
                       const float* __restrict__ W1, const float* __restrict__ W2,
                       bf16* __restrict__ wt) {
  int idx = blockIdx.x * 256 + threadIdx.x;
  if (idx >= 2 * WT_LAYER) return;
  int l = idx / WT_LAYER, r = idx % WT_LAYER;
  float v;
  if (r < 393216) {                       // qkv: 6 x [64 k8][128 n][8 e]
    int jn = r >> 16, t = r & 65535;
    int k8 = t >> 10, u = t & 1023, n = u >> 3, e = u & 7;
    int ncol = jn * 128 + n, k = k8 * 8 + e;
    if (ncol < 256) {
      v = (k < 256) ? Wq[l * 65536 + k * 256 + ncol] : 0.0f;
    } else {
      int u2 = ncol - 256;
      int c = (u2 >> 3) * 4 + (u2 & 3);
      int half = (u2 >> 2) & 1;
      if (k < 256) v = Wkv[l * 131072 + k * 512 + half * 256 + c];
      else         v = We[l * 131072 + (k - 256) * 256 + c];
    }
  } else if (r < 524288) {                // WO region: Wo part (k<256) only
    int rr = r - 393216;
    int jn = rr >> 16, t = rr & 65535;
    int k8 = t >> 10, u = t & 1023, n = u >> 3, e = u & 7;
    int k = k8 * 8 + e;
    if (k >= 256) return;                 // Weff part filled by prep_weff
    v = Wo[l * 65536 + k * 256 + jn * 128 + n];
  } else if (r < 786432) {                // W1: 8 x [32 k8][128 n][8 e]
    int rr = r - 524288;
    int j = rr >> 15, t = rr & 32767;
    int k8 = t >> 10, u = t & 1023, n = u >> 3, e = u & 7;
    v = W1[l * 262144 + (k8 * 8 + e) * 1024 + j * 128 + n];
  } else {                                // W2: 8 x [16 k8][256 n][8 e]
    int rr = r - 786432;
    int j = rr >> 15, t = rr & 32767;
    int k8 = t >> 11, u = t & 2047, n = u >> 3, e = u & 7;
    v = W2[l * 262144 + (j * 128 + k8 * 8 + e) * 256 + n];
  }
  wt[idx] = (bf16)v;
}

// Weff = We_bot @ Wo  (fp32 accumulate), packed into WO region k >= 256
__global__ void prep_weff(const float* __restrict__ We, const float* __restrict__ Wo,
                          bf16* __restrict__ wt) {
  int idx = blockIdx.x * 256 + threadIdx.x;
  if (idx >= 2 * 65536) return;
  int l = idx >> 16, r = idx & 65535;
  int k = r >> 8, n = r & 255;
  const float* wer = We + l * 131072 + (256 + k) * 256;
  const float* wor = Wo + l * 65536 + n;
  float acc = 0.0f;
#pragma unroll 4
  for (int m = 0; m < 256; ++m) acc += wer[m] * wor[m * 256];
  int kf = 256 + k;
  size_t off = (size_t)l * WT_LAYER + WT_WO +
               (n >> 7) * 65536 + (kf >> 3) * 1024 + (n & 127) * 8 + (kf & 7);
  wt[off] = (bf16)acc;
}

// bvec = be @ Wo + bo  -> biasq[1536 + l*256 + n]
__global__ void prep_bvec(const float* __restrict__ be, const float* __restrict__ Wo,
                          const float* __restrict__ bo, float* __restrict__ biasq) {
  int idx = blockIdx.x * 256 + threadIdx.x;
  if (idx >= 512) return;
  int l = idx >> 8, n = idx & 255;
  const float* ber = be + l * 256;
  const float* wor = Wo + l * 65536 + n;
  float acc = bo[l * 256 + n];
#pragma unroll 4
  for (int m = 0; m < 256; ++m) acc += ber[m] * wor[m * 256];
  biasq[1536 + l * 256 + n] = acc;
}

// qkv bias: [2][768] = [bq | interleaved bk/bv]
__global__ void prep_bias(const float* __restrict__ bq, const float* __restrict__ bkv,
                          float* __restrict__ biasq) {
  int i = blockIdx.x * 256 + threadIdx.x;
  if (i >= 1536) return;
  int l = i / 768, n = i % 768;
  float v;
  if (n < 256) v = bq[l * 256 + n];
  else {
    int u2 = n - 256;
    int c = (u2 >> 3) * 4 + (u2 & 3);
    int half = (u2 >> 2) & 1;
    v = bkv[l * 512 + half * 256 + c];
  }
  biasq[i] = v;
}

// x (fp32) -> A2 right half (bf16, stride 512)
__global__ void prep_x(const float* __restrict__ x, bf16* __restrict__ A2) {
  int i = blockIdx.x * 256 + threadIdx.x;
  if (i >= HALF_N * 64) return;
  int row = i >> 6, c = i & 63;
  float4 v = reinterpret_cast<const float4*>(x)[i];
  bf16x4 o;
  o[0] = (bf16)v.x; o[1] = (bf16)v.y; o[2] = (bf16)v.z; o[3] = (bf16)v.w;
  *reinterpret_cast<bf16x4*>(A2 + (size_t)row * 512 + 256 + c * 4) = o;
}

extern "C" void kernel_launch(void* const* d_in, const int* in_sizes, int n_in,
                              void* d_out, int out_size, void* d_ws, size_t ws_size,
                              hipStream_t stream) {
  const float* x     = (const float*)d_in[0];
  const int*   ei    = (const int*)d_in[1];
  const float* ln1_g = (const float*)d_in[2];
  const float* ln1_b = (const float*)d_in[3];
  const float* Wq    = (const float*)d_in[4];
  const float* bq    = (const float*)d_in[5];
  const float* Wkv   = (const float*)d_in[6];
  const float* bkv   = (const float*)d_in[7];
  const float* We    = (const float*)d_in[8];
  const float* be    = (const float*)d_in[9];
  const float* Wo    = (const float*)d_in[10];
  const float* bo    = (const float*)d_in[11];
  const float* g_attn= (const float*)d_in[12];
  const float* ln2_g = (const float*)d_in[13];
  const float* ln2_b = (const float*)d_in[14];
  const float* W1    = (const float*)d_in[15];
  const float* b1    = (const float*)d_in[16];
  const float* W2    = (const float*)d_in[17];
  const float* b2    = (const float*)d_in[18];
  const float* g_ff  = (const float*)d_in[19];
  const float* Wout  = (const float*)d_in[20];
  const float* bout  = (const float*)d_in[21];
  float* out = (float*)d_out;

  char* base = (char*)d_ws;
  float* nodes   = (float*)base;  base += (size_t)N_NODES * DIM * 4;      // 51.2 MB
  bf16*  A2      = (bf16*)base;   base += (size_t)HALF_N * 512 * 2;       // 25.6 MB
  bf16*  xn_bf   = (bf16*)base;   base += (size_t)N_NODES * DIM * 2;      // 25.6 MB
  bf16*  qkv     = (bf16*)base;   base += (size_t)HALF_N * 768 * 2;       // 38.4 MB
  bf16*  agg     = (bf16*)base;   base += (size_t)HALF_N * DIM * 2;       // 12.8 MB
  bf16*  wt      = (bf16*)base;   base += (size_t)2 * WT_LAYER * 2;       // 4.2 MB
  float* biasq   = (float*)base;  base += 2048 * 4;
  int*   deg     = (int*)base;    base += HALF_N * 4;
  int*   ell     = (int*)base;    base += (size_t)HALF_N * MAXDEG * 4;    // 6.4 MB

  // one-time prep
  hipMemcpyAsync(nodes, x, (size_t)N_NODES * DIM * sizeof(float),
                 hipMemcpyDeviceToDevice, stream);
  prep_w<<<(2 * WT_LAYER + 255) / 256, 256, 0, stream>>>(Wq, Wkv, We, Wo, W1, W2, wt);
  prep_weff<<<(2 * 65536 + 255) / 256, 256, 0, stream>>>(We, Wo, wt);
  prep_bvec<<<2, 256, 0, stream>>>(be, Wo, bo, biasq);
  prep_bias<<<6, 256, 0, stream>>>(bq, bkv, biasq);
  prep_x<<<(HALF_N * 64 + 255) / 256, 256, 0, stream>>>(x, A2);
  hipMemsetAsync(deg, 0, HALF_N * sizeof(int), stream);
  ell_build<<<(N_EDGES + 255) / 256, 256, 0, stream>>>(ei, deg, ell);

  const int GP_H = (HALF_N + 63) / 64;    // 391
  const int GP_N = (N_NODES + 63) / 64;   // 782

  for (int l = 0; l < NDEPTH; ++l) {
    const bf16* wl = wt + (size_t)l * WT_LAYER;
    if (l == 0)
      ln0_kernel<<<(HALF_N + 3) / 4, 256, 0, stream>>>(x, ln1_g, ln1_b, A2);
    // qkv = [xn|x] @ qkvT + bias (k/v interleaved cols, N=768)
    gemm_nloop<512, 6><<<GP_H, 512, 0, stream>>>(A2, wl + WT_QKVE, biasq + l * 768, qkv, HALF_N);
    // attention gather (softV only; eB folded via Weff)
    attn_gather<<<(HALF_N + 3) / 4, 256, 0, stream>>>(deg, ell, qkv, agg);
    // attn_out = [agg|x] @ [Wo;Weff] + bvec, fused gr1 + LN2 (ALL rows)
    wo_fused<<<GP_N, 256, 0, stream>>>(agg, A2, wl + WT_WO, biasq + 1536 + l * 256,
                                       bo + l * DIM, deg, g_attn + l * 768,
                                       ln2_g + l * DIM, ln2_b + l * DIM,
                                       nodes, xn_bf, N_NODES);
    // fused FF + gr2 (+LN1next into A2 | +out-proj)
    if (l < NDEPTH - 1) {
      ff_fused<0><<<GP_N, 512, 0, stream>>>(
          xn_bf, wl + WT_W1, b1 + l * 1024, wl + WT_W2, b2 + l * DIM,
          nodes, g_ff + l * 768, ln1_g + (l + 1) * DIM, ln1_b + (l + 1) * DIM, A2,
          nullptr, nullptr, nullptr, N_NODES);
    } else {
      ff_fused<1><<<GP_N, 512, 0, stream>>>(
          xn_bf, wl + WT_W1, b1 + l * 1024, wl + WT_W2, b2 + l * DIM,
          nodes, g_ff + l * 768, nullptr, nullptr, nullptr,
          Wout, bout, out, N_NODES);
    }
  }
}